// Round 2
// baseline (27.688 us; speedup 1.0000x reference)
//
#include <hip/hip_runtime.h>
#include <math.h>

constexpr int BB  = 256;   // batch rows
constexpr int SS  = 512;   // slate size
constexpr int SP2 = SS + 2;

__device__ __forceinline__ float block_reduce512(float v, volatile float* sm) {
    // 512 threads = 8 waves of 64
    #pragma unroll
    for (int off = 32; off > 0; off >>= 1)
        v += __shfl_down(v, off, 64);
    const int wid  = threadIdx.x >> 6;
    const int lane = threadIdx.x & 63;
    __syncthreads();                 // protect sm reuse across calls
    if (lane == 0) sm[wid] = v;
    __syncthreads();
    return ((sm[0] + sm[1]) + (sm[2] + sm[3])) + ((sm[4] + sm[5]) + (sm[6] + sm[7]));
}

__device__ __forceinline__ float sigmoidf_(float x) {
    return 1.0f / (1.0f + expf(-x));   // saturates cleanly to 0/1 in fp32
}

__global__ __launch_bounds__(512)
void ndcg_fused_kernel(const float* __restrict__ y_pred,
                       const float* __restrict__ y_true,
                       const int*   __restrict__ qid,
                       const int*   __restrict__ indices,
                       const int*   __restrict__ num_pos,
                       const int*   __restrict__ num_item,
                       const float* __restrict__ ideal_dcg,
                       const float* __restrict__ u_buf,
                       const float* __restrict__ v_buf,
                       const float* __restrict__ lambda_q,
                       const float* __restrict__ r_q,
                       const float* __restrict__ s_q,
                       float* __restrict__ ws_row,
                       float* __restrict__ ws_a,
                       int*   __restrict__ counter,
                       float* __restrict__ out) {
    __shared__ float sh_ys[SS] __attribute__((aligned(16)));  // yp, -1e4 at padded
    __shared__ float sh_G[SS];                                // gain, 0 at padded
    __shared__ float sm[8];
    __shared__ int   smi[8];
    __shared__ int   lastSh;

    const int b = blockIdx.x;
    const int t = threadIdx.x;   // one item per thread

    // ---- stage row + prefetch phase-C operands ----
    const float yt     = y_true[b * SS + t];
    const float ypv    = y_pred[b * SS + t];
    const bool  finite = (yt != -1.0f);
    const float fin    = finite ? 1.0f : 0.0f;
    sh_ys[t] = finite ? ypv : -1.0e4f;
    sh_G[t]  = finite ? (exp2f(fmaxf(yt, 0.0f)) - 1.0f) : 0.0f;

    const int   qf    = qid[b * SS + t] + 1;
    const int   idf   = indices[b * SS + t] + 1;
    const float u_old = u_buf[qf * SP2 + idf];   // coalesced gather, in flight
    const float v_old = v_buf[qf * SP2 + idf];   // during the hinge loop
    const int   qb    = qid[b * SS] + 1;
    const float lam   = lambda_q[qb];
    const float ni    = (float)num_item[b];
    const float sqv   = s_q[qb];

    __syncthreads();

    // ---- n_fin (sum) and jmax (max finite index) in one pass ----
    float n_fin;
    int   jmax;
    {
        float v = fin;
        int   m = finite ? t : -1;
        #pragma unroll
        for (int off = 32; off > 0; off >>= 1) {
            v += __shfl_down(v, off, 64);
            m  = max(m, __shfl_down(m, off, 64));
        }
        const int wid = t >> 6, lane = t & 63;
        if (lane == 0) { sm[wid] = v; smi[wid] = m; }
        __syncthreads();
        n_fin = ((sm[0] + sm[1]) + (sm[2] + sm[3])) + ((sm[4] + sm[5]) + (sm[6] + sm[7]));
        jmax  = max(max(max(smi[0], smi[1]), max(smi[2], smi[3])),
                    max(max(smi[4], smi[5]), max(smi[6], smi[7])));
    }

    // ---- pairwise squared hinge g[t] ----
    // padded j contribute 0 via the -1e4 sentinel; only need j <= jmax
    const float ypz = fin * ypv;          // yp zeroed at padded (reference semantics)
    const float yi1 = 1.0f - ypz;         // d = yp[j] - yp[i] + 1
    const int j4cnt = (jmax + 4) >> 2;    // ceil((jmax+1)/4), block-uniform
    const float4* ys4 = (const float4*)sh_ys;
    float a0 = 0.f, a1 = 0.f, a2 = 0.f, a3 = 0.f;
    for (int j = 0; j < j4cnt; ++j) {     // uniform-address LDS broadcast reads
        const float4 y = ys4[j];
        const float h0 = fmaxf(y.x + yi1, 0.0f);
        const float h1 = fmaxf(y.y + yi1, 0.0f);
        const float h2 = fmaxf(y.z + yi1, 0.0f);
        const float h3 = fmaxf(y.w + yi1, 0.0f);
        a0 = fmaf(h0, h0, a0); a1 = fmaf(h1, h1, a1);
        a2 = fmaf(h2, h2, a2); a3 = fmaf(h3, h3, a3);
    }
    const float g = fin * (((a0 + a1) + (a2 + a3)) / n_fin) + 1e-10f;

    // ---- per-item phase-C terms ----
    const float nug   = u_old - g;                        // u_old - stopgrad(g)
    const float v_new = 0.9f * v_old + 0.1f * nug;        // GAMMA_V
    const float g_u   = u_old - 0.01f * v_new;            // u_new (ETA1)
    const float t2    = fmaf(ni, g_u, 2.0f);              // 2 + ni*g_u (>0)
    const float l2t   = log2f(t2);
    const float Gs    = sh_G[t];

    float nfg = Gs * ni / (l2t * l2t * t2 * 0.6931471805599453f);

    const float pld  = finite ? (ypv - lam) : 0.0f;
    const float sig1 = sigmoidf_(pld * 1000.0f);          // pld / TAU1
    const float siga = sigmoidf_(pld * 2.0f);             // pld * SIG_ALPHA
    nfg *= 2.0f * siga;                                    // C_SIG * sig_a
    const float w1  = 2.0f * siga * (1.0f - siga);
    const float tt  = sig1 * (1.0f - sig1) * 1000.0f;      // /TAU1
    const float fgu = -Gs / l2t;

    float Shess = fin * tt;
    float Sphi  = fin * (Gs / l2t);
    float Shy   = fin * tt * ypz;
    float P1    = nfg * g;
    float P2    = w1 * fgu * ypz;
    float P3    = w1 * fgu;
    Shess = block_reduce512(Shess, sm);
    Sphi  = block_reduce512(Sphi,  sm);
    Shy   = block_reduce512(Shy,   sm);
    P1    = block_reduce512(P1,    sm);
    P2    = block_reduce512(P2,    sm);
    P3    = block_reduce512(P3,    sm);

    if (t == 0) {
        const float L_hess  = 1e-4f + Shess / n_fin;               // TAU2 + ...
        const float nsp     = L_hess * sqv + Sphi / n_fin;
        const float r_new   = 0.9f * r_q[qb] + 0.1f * nsp;         // GAMMA_R
        const float s_new   = sqv - 0.01f * r_new;                 // ETA1
        const float hess    = (Shy / n_fin) / s_new;
        const float row_sum = P1 + P2 - hess * P3;
        __hip_atomic_store(&ws_row[b], row_sum * (1.0f / (float)SS),
                           __ATOMIC_RELAXED, __HIP_MEMORY_SCOPE_AGENT);
        __hip_atomic_store(&ws_a[b], (float)num_pos[b] / (ideal_dcg[b] + 1e-10f),
                           __ATOMIC_RELAXED, __HIP_MEMORY_SCOPE_AGENT);
        __threadfence();
        const int old = __hip_atomic_fetch_add(counter, 1,
                           __ATOMIC_ACQ_REL, __HIP_MEMORY_SCOPE_AGENT);
        lastSh = (old == BB - 1) ? 1 : 0;
    }
    __syncthreads();

    // ---- last block: deterministic fixed-order final reduction ----
    if (lastSh) {
        float r = 0.f, a = 0.f;
        if (t < BB) {
            r = __hip_atomic_load(&ws_row[t], __ATOMIC_RELAXED, __HIP_MEMORY_SCOPE_AGENT);
            a = __hip_atomic_load(&ws_a[t],  __ATOMIC_RELAXED, __HIP_MEMORY_SCOPE_AGENT);
        }
        r = block_reduce512(r, sm);
        a = block_reduce512(a, sm);
        if (t == 0)
            out[0] = (a * (1.0f / (float)BB)) * (r * (1.0f / (float)BB));
    }
}

extern "C" void kernel_launch(void* const* d_in, const int* in_sizes, int n_in,
                              void* d_out, int out_size, void* d_ws, size_t ws_size,
                              hipStream_t stream) {
    const float* y_pred    = (const float*)d_in[0];
    const float* y_true    = (const float*)d_in[1];
    const int*   qid       = (const int*)  d_in[2];
    const int*   indices   = (const int*)  d_in[3];
    const int*   num_pos   = (const int*)  d_in[4];
    const int*   num_item  = (const int*)  d_in[5];
    const float* ideal_dcg = (const float*)d_in[6];
    const float* u_buf     = (const float*)d_in[7];
    const float* v_buf     = (const float*)d_in[8];
    const float* lambda_q  = (const float*)d_in[9];
    // d_in[10] = z_q (unused by the forward path)
    const float* r_q       = (const float*)d_in[11];
    const float* s_q       = (const float*)d_in[12];

    float* wsf     = (float*)d_ws;          // [0,BB) row means, [BB,2BB) num_pos/idcg
    int*   counter = (int*)(wsf + 2 * BB);

    hipMemsetAsync(counter, 0, sizeof(int), stream);   // graph-capture-safe memset node
    ndcg_fused_kernel<<<BB, 512, 0, stream>>>(y_pred, y_true, qid, indices,
                                              num_pos, num_item, ideal_dcg,
                                              u_buf, v_buf, lambda_q, r_q, s_q,
                                              wsf, wsf + BB, counter, (float*)d_out);
}

// Round 3
// 18.265 us; speedup vs baseline: 1.5159x; 1.5159x over previous
//
#include <hip/hip_runtime.h>
#include <math.h>

constexpr int BB  = 256;   // batch rows
constexpr int SS  = 512;   // slate size
constexpr int SP2 = SS + 2;

// reduce two values across 256 threads (4 waves) with one LDS roundtrip
__device__ __forceinline__ float2 block_reduce256_x2(float v, float w,
                                                     volatile float* sm) {
    #pragma unroll
    for (int off = 32; off > 0; off >>= 1) {
        v += __shfl_down(v, off, 64);
        w += __shfl_down(w, off, 64);
    }
    const int wid  = threadIdx.x >> 6;
    const int lane = threadIdx.x & 63;
    __syncthreads();                 // protect sm reuse across calls
    if (lane == 0) { sm[wid] = v; sm[4 + wid] = w; }
    __syncthreads();
    return make_float2((sm[0] + sm[1]) + (sm[2] + sm[3]),
                       (sm[4] + sm[5]) + (sm[6] + sm[7]));
}

__device__ __forceinline__ float sigmoidf_(float x) {
    return 1.0f / (1.0f + expf(-x));   // saturates cleanly to 0/1 in fp32
}

__global__ __launch_bounds__(256)
void ndcg_row_kernel(const float* __restrict__ y_pred,
                     const float* __restrict__ y_true,
                     const int*   __restrict__ qid,
                     const int*   __restrict__ indices,
                     const int*   __restrict__ num_pos,
                     const int*   __restrict__ num_item,
                     const float* __restrict__ ideal_dcg,
                     const float* __restrict__ u_buf,
                     const float* __restrict__ v_buf,
                     const float* __restrict__ lambda_q,
                     const float* __restrict__ r_q,
                     const float* __restrict__ s_q,
                     float2* __restrict__ ws) {
    __shared__ float sh_ys[SS] __attribute__((aligned(16)));  // yp, -1e4 at padded
    __shared__ float sm[8];

    const int b = blockIdx.x;
    const int t = threadIdx.x;   // items t and t+256

    // ---- stage row (only the sentinel copy goes to LDS) ----
    float yp[2], fin[2], Gs[2];
    #pragma unroll
    for (int k = 0; k < 2; ++k) {
        const int s    = t + k * 256;
        const float yt = y_true[b * SS + s];
        const float yv = y_pred[b * SS + s];
        const bool  fi = (yt != -1.0f);
        yp[k]  = yv;
        fin[k] = fi ? 1.0f : 0.0f;
        Gs[k]  = fi ? (exp2f(fmaxf(yt, 0.0f)) - 1.0f) : 0.0f;
        sh_ys[s] = fi ? yv : -1.0e4f;
    }

    // ---- prefetch phase-C operands (in flight during the hinge loop) ----
    int   uix[2];
    float u_old[2], v_old[2];
    #pragma unroll
    for (int k = 0; k < 2; ++k) {
        const int s = t + k * 256;
        uix[k] = (qid[b * SS + s] + 1) * SP2 + (indices[b * SS + s] + 1);
        u_old[k] = u_buf[uix[k]];
        v_old[k] = v_buf[uix[k]];
    }
    const int   qb  = qid[b * SS] + 1;
    const float lam = lambda_q[qb];
    const float ni  = (float)num_item[b];
    const float sqv = s_q[qb];

    __syncthreads();

    // ---- pairwise squared hinge: ONE j-loop feeding BOTH items ----
    const float yi1_0 = 1.0f - fin[0] * yp[0];   // d = yp[j] - yp[i] + 1
    const float yi1_1 = 1.0f - fin[1] * yp[1];
    const float4* ys4 = (const float4*)sh_ys;
    float a00 = 0.f, a01 = 0.f, a02 = 0.f, a03 = 0.f;
    float a10 = 0.f, a11 = 0.f, a12 = 0.f, a13 = 0.f;
    #pragma unroll 4
    for (int j = 0; j < SS / 4; ++j) {           // uniform-address LDS broadcast
        const float4 y = ys4[j];
        float h;
        h = fmaxf(y.x + yi1_0, 0.0f); a00 = fmaf(h, h, a00);
        h = fmaxf(y.y + yi1_0, 0.0f); a01 = fmaf(h, h, a01);
        h = fmaxf(y.z + yi1_0, 0.0f); a02 = fmaf(h, h, a02);
        h = fmaxf(y.w + yi1_0, 0.0f); a03 = fmaf(h, h, a03);
        h = fmaxf(y.x + yi1_1, 0.0f); a10 = fmaf(h, h, a10);
        h = fmaxf(y.y + yi1_1, 0.0f); a11 = fmaf(h, h, a11);
        h = fmaxf(y.z + yi1_1, 0.0f); a12 = fmaf(h, h, a12);
        h = fmaxf(y.w + yi1_1, 0.0f); a13 = fmaf(h, h, a13);
    }

    // ---- n_fin AFTER the hinge loop (division was deferred) ----
    const float2 nf2 = block_reduce256_x2(fin[0] + fin[1], 0.0f, sm);
    const float n_fin = nf2.x;
    float g[2];
    g[0] = fin[0] * (((a00 + a01) + (a02 + a03)) / n_fin) + 1e-10f;
    g[1] = fin[1] * (((a10 + a11) + (a12 + a13)) / n_fin) + 1e-10f;

    // ---- per-item phase-C terms ----
    float Shess = 0.f, Sphi = 0.f, Shy = 0.f, P1 = 0.f, P2 = 0.f, P3 = 0.f;
    #pragma unroll
    for (int k = 0; k < 2; ++k) {
        const float nug   = u_old[k] - g[k];                 // u_old - stopgrad(g)
        const float v_new = 0.9f * v_old[k] + 0.1f * nug;    // GAMMA_V
        const float g_u   = u_old[k] - 0.01f * v_new;        // u_new (ETA1)
        const float t2    = fmaf(ni, g_u, 2.0f);             // 2 + ni*g_u (>0)
        const float l2t   = log2f(t2);

        float nfg = Gs[k] * ni / (l2t * l2t * t2 * 0.6931471805599453f);

        const float pld  = (fin[k] != 0.0f) ? (yp[k] - lam) : 0.0f;
        const float sig1 = sigmoidf_(pld * 1000.0f);         // pld / TAU1
        const float siga = sigmoidf_(pld * 2.0f);            // pld * SIG_ALPHA
        nfg *= 2.0f * siga;                                   // C_SIG * sig_a
        const float w1  = 2.0f * siga * (1.0f - siga);
        const float tt  = sig1 * (1.0f - sig1) * 1000.0f;     // /TAU1
        const float fgu = -Gs[k] / l2t;
        const float ypz = fin[k] * yp[k];

        Shess += fin[k] * tt;
        Sphi  += fin[k] * (Gs[k] / l2t);
        Shy   += fin[k] * tt * ypz;
        P1  = fmaf(nfg, g[k], P1);
        P2 += w1 * fgu * ypz;
        P3 += w1 * fgu;
    }
    const float2 rA = block_reduce256_x2(Shess, Sphi, sm);
    const float2 rB = block_reduce256_x2(Shy,   P1,  sm);
    const float2 rC = block_reduce256_x2(P2,    P3,  sm);

    if (t == 0) {
        const float L_hess  = 1e-4f + rA.x / n_fin;                // TAU2 + ...
        const float nsp     = L_hess * sqv + rA.y / n_fin;
        const float r_new   = 0.9f * r_q[qb] + 0.1f * nsp;         // GAMMA_R
        const float s_new   = sqv - 0.01f * r_new;                 // ETA1
        const float hess    = (rB.x / n_fin) / s_new;
        const float row_sum = rB.y + rC.x - hess * rC.y;
        ws[b] = make_float2(row_sum * (1.0f / (float)SS),
                            (float)num_pos[b] / (ideal_dcg[b] + 1e-10f));
    }
}

__global__ __launch_bounds__(64)
void ndcg_final_kernel(const float2* __restrict__ ws, float* __restrict__ out) {
    const int t = threadIdx.x;     // single wave: no LDS, no syncthreads
    float r = 0.f, a = 0.f;
    #pragma unroll
    for (int k = 0; k < 4; ++k) {
        const float2 p = ws[t + 64 * k];
        r += p.x; a += p.y;
    }
    #pragma unroll
    for (int off = 32; off > 0; off >>= 1) {
        r += __shfl_down(r, off, 64);
        a += __shfl_down(a, off, 64);
    }
    if (t == 0)
        out[0] = (a * (1.0f / (float)BB)) * (r * (1.0f / (float)BB));
}

extern "C" void kernel_launch(void* const* d_in, const int* in_sizes, int n_in,
                              void* d_out, int out_size, void* d_ws, size_t ws_size,
                              hipStream_t stream) {
    const float* y_pred    = (const float*)d_in[0];
    const float* y_true    = (const float*)d_in[1];
    const int*   qid       = (const int*)  d_in[2];
    const int*   indices   = (const int*)  d_in[3];
    const int*   num_pos   = (const int*)  d_in[4];
    const int*   num_item  = (const int*)  d_in[5];
    const float* ideal_dcg = (const float*)d_in[6];
    const float* u_buf     = (const float*)d_in[7];
    const float* v_buf     = (const float*)d_in[8];
    const float* lambda_q  = (const float*)d_in[9];
    // d_in[10] = z_q (unused by the forward path)
    const float* r_q       = (const float*)d_in[11];
    const float* s_q       = (const float*)d_in[12];

    float2* ws = (float2*)d_ws;   // [BB] per-row {row_mean, num_pos/idcg}

    ndcg_row_kernel<<<BB, 256, 0, stream>>>(y_pred, y_true, qid, indices,
                                            num_pos, num_item, ideal_dcg,
                                            u_buf, v_buf, lambda_q, r_q, s_q, ws);
    ndcg_final_kernel<<<1, 64, 0, stream>>>(ws, (float*)d_out);
}

// Round 4
// 16.983 us; speedup vs baseline: 1.6303x; 1.0755x over previous
//
#include <hip/hip_runtime.h>
#include <math.h>

constexpr int BB  = 256;   // batch rows
constexpr int SS  = 512;   // slate size
constexpr int SP2 = SS + 2;

// sum + max across 256 threads (4 waves), one LDS roundtrip
__device__ __forceinline__ float2 block_red_sum_max(float v, float m,
                                                    volatile float* sm) {
    #pragma unroll
    for (int off = 32; off > 0; off >>= 1) {
        v += __shfl_down(v, off, 64);
        m  = fmaxf(m, __shfl_down(m, off, 64));
    }
    const int wid  = threadIdx.x >> 6;
    const int lane = threadIdx.x & 63;
    __syncthreads();
    if (lane == 0) { sm[wid] = v; sm[4 + wid] = m; }
    __syncthreads();
    return make_float2((sm[0] + sm[1]) + (sm[2] + sm[3]),
                       fmaxf(fmaxf(sm[4], sm[5]), fmaxf(sm[6], sm[7])));
}

// three sums across 256 threads, one LDS roundtrip
__device__ __forceinline__ float3 block_red3(float a, float b, float c,
                                             volatile float* sm) {
    #pragma unroll
    for (int off = 32; off > 0; off >>= 1) {
        a += __shfl_down(a, off, 64);
        b += __shfl_down(b, off, 64);
        c += __shfl_down(c, off, 64);
    }
    const int wid  = threadIdx.x >> 6;
    const int lane = threadIdx.x & 63;
    __syncthreads();
    if (lane == 0) { sm[wid] = a; sm[4 + wid] = b; sm[8 + wid] = c; }
    __syncthreads();
    return make_float3((sm[0] + sm[1]) + (sm[2] + sm[3]),
                       (sm[4] + sm[5]) + (sm[6] + sm[7]),
                       (sm[8] + sm[9]) + (sm[10] + sm[11]));
}

__device__ __forceinline__ float sigmoidf_(float x) {
    return 1.0f / (1.0f + expf(-x));   // saturates cleanly to 0/1 in fp32
}

__global__ __launch_bounds__(256)
void ndcg_row_kernel(const float* __restrict__ y_pred,
                     const float* __restrict__ y_true,
                     const int*   __restrict__ qid,
                     const int*   __restrict__ indices,
                     const int*   __restrict__ num_pos,
                     const int*   __restrict__ num_item,
                     const float* __restrict__ ideal_dcg,
                     const float* __restrict__ u_buf,
                     const float* __restrict__ v_buf,
                     const float* __restrict__ lambda_q,
                     const float* __restrict__ r_q,
                     const float* __restrict__ s_q,
                     float2* __restrict__ ws) {
    __shared__ float sh_ys[SS] __attribute__((aligned(16)));  // yp, -1e4 at padded
    __shared__ float sm[12];

    const int b = blockIdx.x;
    const int t = threadIdx.x;   // items 2t and 2t+1 (vectorizable pairs)

    // ---- vectorized stage ----
    const float2 yt2 = *(const float2*)&y_true[b * SS + 2 * t];
    const float2 yp2 = *(const float2*)&y_pred[b * SS + 2 * t];
    const int2   qd2 = *(const int2*)  &qid[b * SS + 2 * t];
    const int2   ix2 = *(const int2*)  &indices[b * SS + 2 * t];

    const bool  fi0 = (yt2.x != -1.0f), fi1 = (yt2.y != -1.0f);
    const float f0  = fi0 ? 1.0f : 0.0f, f1 = fi1 ? 1.0f : 0.0f;
    float2 zs;
    zs.x = fi0 ? yp2.x : -1.0e4f;
    zs.y = fi1 ? yp2.y : -1.0e4f;
    *(float2*)&sh_ys[2 * t] = zs;
    const float G0 = fi0 ? (exp2f(fmaxf(yt2.x, 0.0f)) - 1.0f) : 0.0f;
    const float G1 = fi1 ? (exp2f(fmaxf(yt2.y, 0.0f)) - 1.0f) : 0.0f;

    // ---- prefetch phase-C gathers (in flight during hinge) ----
    const int   ui0 = (qd2.x + 1) * SP2 + (ix2.x + 1);
    const int   ui1 = (qd2.y + 1) * SP2 + (ix2.y + 1);
    const float u_old0 = u_buf[ui0], v_old0 = v_buf[ui0];
    const float u_old1 = u_buf[ui1], v_old1 = v_buf[ui1];
    const int   qb  = qid[b * SS] + 1;
    const float lam = lambda_q[qb];
    const float ni  = (float)num_item[b];
    const float sqv = s_q[qb];

    __syncthreads();

    // ---- n_fin + jmax in ONE roundtrip (float-encoded index, exact) ----
    const float mI = fi1 ? (float)(2 * t + 1) : (fi0 ? (float)(2 * t) : -1.0f);
    const float2 nm = block_red_sum_max(f0 + f1, mI, sm);
    const float n_fin = nm.x;
    const int   jmax  = (int)nm.y;
    const int   j4cnt = (jmax + 4) >> 2;      // ceil((jmax+1)/4), block-uniform

    // ---- pairwise squared hinge: one j-loop, both items ----
    const float yi1_0 = 1.0f - f0 * yp2.x;    // d = yp[j] - yp[i] + 1
    const float yi1_1 = 1.0f - f1 * yp2.y;
    const float4* ys4 = (const float4*)sh_ys;
    float a00 = 0.f, a01 = 0.f, a02 = 0.f, a03 = 0.f;
    float a10 = 0.f, a11 = 0.f, a12 = 0.f, a13 = 0.f;
    #pragma unroll 4
    for (int j = 0; j < j4cnt; ++j) {         // uniform-address LDS broadcast
        const float4 y = ys4[j];
        float h;
        h = fmaxf(y.x + yi1_0, 0.0f); a00 = fmaf(h, h, a00);
        h = fmaxf(y.y + yi1_0, 0.0f); a01 = fmaf(h, h, a01);
        h = fmaxf(y.z + yi1_0, 0.0f); a02 = fmaf(h, h, a02);
        h = fmaxf(y.w + yi1_0, 0.0f); a03 = fmaf(h, h, a03);
        h = fmaxf(y.x + yi1_1, 0.0f); a10 = fmaf(h, h, a10);
        h = fmaxf(y.y + yi1_1, 0.0f); a11 = fmaf(h, h, a11);
        h = fmaxf(y.z + yi1_1, 0.0f); a12 = fmaf(h, h, a12);
        h = fmaxf(y.w + yi1_1, 0.0f); a13 = fmaf(h, h, a13);
    }
    const float inv_nfin = 1.0f / n_fin;
    float g[2];
    g[0] = f0 * (((a00 + a01) + (a02 + a03)) * inv_nfin) + 1e-10f;
    g[1] = f1 * (((a10 + a11) + (a12 + a13)) * inv_nfin) + 1e-10f;

    // ---- per-item phase-C terms ----
    const float uo[2] = {u_old0, u_old1}, vo[2] = {v_old0, v_old1};
    const float fn[2] = {f0, f1}, Gk[2] = {G0, G1};
    const float yv[2] = {yp2.x, yp2.y};
    float Shess = 0.f, Sphi = 0.f, Shy = 0.f, P1 = 0.f, P2 = 0.f, P3 = 0.f;
    #pragma unroll
    for (int k = 0; k < 2; ++k) {
        const float nug   = uo[k] - g[k];                 // u_old - stopgrad(g)
        const float v_new = 0.9f * vo[k] + 0.1f * nug;    // GAMMA_V
        const float g_u   = uo[k] - 0.01f * v_new;        // u_new (ETA1)
        const float t2    = fmaf(ni, g_u, 2.0f);          // 2 + ni*g_u (>0)
        const float l2t   = log2f(t2);
        const float rl2t  = 1.0f / l2t;

        float nfg = Gk[k] * ni / (l2t * l2t * t2 * 0.6931471805599453f);

        const float pld  = (fn[k] != 0.0f) ? (yv[k] - lam) : 0.0f;
        const float sig1 = sigmoidf_(pld * 1000.0f);      // pld / TAU1
        const float siga = sigmoidf_(pld * 2.0f);         // pld * SIG_ALPHA
        nfg *= 2.0f * siga;                                // C_SIG * sig_a
        const float w1  = 2.0f * siga * (1.0f - siga);
        const float tt  = sig1 * (1.0f - sig1) * 1000.0f;  // /TAU1
        const float fgu = -Gk[k] * rl2t;
        const float ypz = fn[k] * yv[k];

        Shess += fn[k] * tt;
        Sphi  += fn[k] * (Gk[k] * rl2t);
        Shy   += fn[k] * tt * ypz;
        P1  = fmaf(nfg, g[k], P1);
        P2 += w1 * fgu * ypz;
        P3 += w1 * fgu;
    }
    const float3 rA = block_red3(Shess, Sphi, Shy, sm);
    const float3 rB = block_red3(P1,    P2,   P3,  sm);

    if (t == 0) {
        const float L_hess  = 1e-4f + rA.x * inv_nfin;             // TAU2 + ...
        const float nsp     = L_hess * sqv + rA.y * inv_nfin;
        const float r_new   = 0.9f * r_q[qb] + 0.1f * nsp;         // GAMMA_R
        const float s_new   = sqv - 0.01f * r_new;                 // ETA1
        const float hess    = (rA.z * inv_nfin) / s_new;
        const float row_sum = rB.x + rB.y - hess * rB.z;
        ws[b] = make_float2(row_sum * (1.0f / (float)SS),
                            (float)num_pos[b] / (ideal_dcg[b] + 1e-10f));
    }
}

__global__ __launch_bounds__(64)
void ndcg_final_kernel(const float2* __restrict__ ws, float* __restrict__ out) {
    const int t = threadIdx.x;     // single wave: no LDS, no syncthreads
    float r = 0.f, a = 0.f;
    #pragma unroll
    for (int k = 0; k < 4; ++k) {
        const float2 p = ws[t + 64 * k];
        r += p.x; a += p.y;
    }
    #pragma unroll
    for (int off = 32; off > 0; off >>= 1) {
        r += __shfl_down(r, off, 64);
        a += __shfl_down(a, off, 64);
    }
    if (t == 0)
        out[0] = (a * (1.0f / (float)BB)) * (r * (1.0f / (float)BB));
}

extern "C" void kernel_launch(void* const* d_in, const int* in_sizes, int n_in,
                              void* d_out, int out_size, void* d_ws, size_t ws_size,
                              hipStream_t stream) {
    const float* y_pred    = (const float*)d_in[0];
    const float* y_true    = (const float*)d_in[1];
    const int*   qid       = (const int*)  d_in[2];
    const int*   indices   = (const int*)  d_in[3];
    const int*   num_pos   = (const int*)  d_in[4];
    const int*   num_item  = (const int*)  d_in[5];
    const float* ideal_dcg = (const float*)d_in[6];
    const float* u_buf     = (const float*)d_in[7];
    const float* v_buf     = (const float*)d_in[8];
    const float* lambda_q  = (const float*)d_in[9];
    // d_in[10] = z_q (unused by the forward path)
    const float* r_q       = (const float*)d_in[11];
    const float* s_q       = (const float*)d_in[12];

    float2* ws = (float2*)d_ws;   // [BB] per-row {row_mean, num_pos/idcg}

    ndcg_row_kernel<<<BB, 256, 0, stream>>>(y_pred, y_true, qid, indices,
                                            num_pos, num_item, ideal_dcg,
                                            u_buf, v_buf, lambda_q, r_q, s_q, ws);
    ndcg_final_kernel<<<1, 64, 0, stream>>>(ws, (float*)d_out);
}